// Round 3
// baseline (624.437 us; speedup 1.0000x reference)
//
#include <hip/hip_runtime.h>
#include <hip/hip_bf16.h>

// Problem constants (DeltaNet_6614249636545)
#define BB 2
#define TT 4096
#define HH 16
#define DKk 128
#define DVv 128
#define HIDD 2048
#define CC 64
#define NN 64          // TT / CC
#define GG 8           // dv column groups in scan kernel
#define QSCALE 0.08838834764831845f  // 128^-0.5

static __device__ __forceinline__ unsigned short f2bf(float f) {
  unsigned u = __float_as_uint(f);
  u += 0x7fffu + ((u >> 16) & 1u);   // round-to-nearest-even
  return (unsigned short)(u >> 16);
}
static __device__ __forceinline__ float bf2f(unsigned short s) {
  return __uint_as_float(((unsigned)s) << 16);
}
static __device__ __forceinline__ unsigned cvtpk(float lo, float hi) {
  unsigned r;
  asm("v_cvt_pk_bf16_f32 %0, %1, %2" : "=v"(r) : "v"(lo), "v"(hi));
  return r;
}

// Barrier that drains ONLY LDS (lgkmcnt), leaving global loads in flight.
static __device__ __forceinline__ void barrier_lds_only() {
  asm volatile("s_waitcnt lgkmcnt(0)\n\ts_barrier" ::: "memory");
}

typedef short bf8 __attribute__((ext_vector_type(8)));
typedef short bf4 __attribute__((ext_vector_type(4)));
typedef float f4 __attribute__((ext_vector_type(4)));

// pack 4 floats -> 4 bf16, typed as shorts so LDS read/write aliasing is
// visible to the compiler (ds_write -> ds_read dependency tracked).
static __device__ __forceinline__ bf4 pack_bf4(float a, float b, float c, float d) {
  union { uint2 u; bf4 s; } t;
  t.u.x = cvtpk(a, b);
  t.u.y = cvtpk(c, d);
  return t.s;
}

// ---------------------------------------------------------------------------
// K0: transpose + bf16-cast projection weights: W[k][h] fp32 -> Wt[h][k] bf16
// ---------------------------------------------------------------------------
__global__ __launch_bounds__(256) void k0_wt(
    const float* __restrict__ Wb, const float* __restrict__ Wg,
    unsigned short* __restrict__ Wtb, unsigned short* __restrict__ Wtg) {
  int blk = blockIdx.x;
  const float* W = (blk < 8) ? Wb : Wg;
  unsigned short* Wt = (blk < 8) ? Wtb : Wtg;
  int k0 = (blk & 7) * 256;
  int tid = threadIdx.x;
  __shared__ unsigned short st[16][272];
  const float* p = W + (size_t)(k0 + tid) * HH;
#pragma unroll
  for (int h4 = 0; h4 < 4; h4++) {
    float4 x = *(const float4*)(p + h4 * 4);
    st[h4 * 4 + 0][tid] = f2bf(x.x);
    st[h4 * 4 + 1][tid] = f2bf(x.y);
    st[h4 * 4 + 2][tid] = f2bf(x.z);
    st[h4 * 4 + 3][tid] = f2bf(x.w);
  }
  __syncthreads();
  int h = tid >> 4, c = (tid & 15) << 4;
#pragma unroll
  for (int j = 0; j < 16; j++)
    Wt[(size_t)h * HIDD + k0 + c + j] = st[h][c + j];
}

// ---------------------------------------------------------------------------
// K0p: per-head transpose of o_proj_w: P[h][v][d] fp32 -> Ppt[h][d][v] bf16.
// ---------------------------------------------------------------------------
__global__ __launch_bounds__(256) void k0p_pt(
    const float* __restrict__ opw, unsigned short* __restrict__ Ppt) {
  int h = blockIdx.x;
  int tid = threadIdx.x;
  __shared__ unsigned short sp[128 * 132];
  const float* P = opw + (size_t)h * (DVv * DKk);
  for (int it = 0; it < 16; it++) {
    int idx = it * 256 + tid;            // 4096 float4 quads
    int vv = idx >> 5, d4 = (idx & 31) << 2;
    float4 x = *(const float4*)(P + vv * 128 + d4);
    sp[vv * 132 + d4 + 0] = f2bf(x.x);
    sp[vv * 132 + d4 + 1] = f2bf(x.y);
    sp[vv * 132 + d4 + 2] = f2bf(x.z);
    sp[vv * 132 + d4 + 3] = f2bf(x.w);
  }
  __syncthreads();
  unsigned short* dst = Ppt + (size_t)h * (DVv * DKk);
  for (int it = 0; it < 8; it++) {
    int idx = it * 256 + tid;            // 2048 groups of 8
    int d = idx >> 4, v8 = (idx & 15) << 3;
    unsigned short tmp[8];
#pragma unroll
    for (int j = 0; j < 8; j++) tmp[j] = sp[(v8 + j) * 132 + d];
    *(uint4*)&dst[d * 128 + v8] = *(uint4*)tmp;
  }
}

// ---------------------------------------------------------------------------
// K1 (MFMA): beta = sigmoid(hab @ Wb), graw = hg @ Wg as skinny GEMM.
// ---------------------------------------------------------------------------
__global__ __launch_bounds__(256) void k1_beta_g(
    const float* __restrict__ hab, const float* __restrict__ hg,
    const unsigned short* __restrict__ Wtb, const unsigned short* __restrict__ Wtg,
    float* __restrict__ beta, float* __restrict__ graw) {
  int tile = blockIdx.x;               // 512 tiles of 16 tokens
  int tid = threadIdx.x;
  int w = tid >> 6, lane = tid & 63;
  int proj = w >> 1, ks = w & 1;
  int n16 = lane & 15, qd = lane >> 4;
  const float* hid = proj ? hg : hab;
  const unsigned short* Wt = proj ? Wtg : Wtb;
  size_t rowbase = (size_t)(tile * 16 + n16) * HIDD;
  int k0 = ks * 1024;

  f4 acc = {0.f, 0.f, 0.f, 0.f};
  for (int s = 0; s < 32; s++) {
    int kk = k0 + s * 32 + qd * 8;
    const float* hp = hid + rowbase + kk;
    float4 h0 = *(const float4*)hp;
    float4 h1 = *(const float4*)(hp + 4);
    bf8 a;
    a[0] = (short)f2bf(h0.x); a[1] = (short)f2bf(h0.y);
    a[2] = (short)f2bf(h0.z); a[3] = (short)f2bf(h0.w);
    a[4] = (short)f2bf(h1.x); a[5] = (short)f2bf(h1.y);
    a[6] = (short)f2bf(h1.z); a[7] = (short)f2bf(h1.w);
    bf8 b = *(const bf8*)&Wt[(size_t)n16 * HIDD + kk];
    acc = __builtin_amdgcn_mfma_f32_16x16x32_bf16(a, b, acc, 0, 0, 0);
  }

  __shared__ float red[2][16][17];
  if (ks == 1) {
#pragma unroll
    for (int r = 0; r < 4; r++) red[proj][qd * 4 + r][n16] = acc[r];
  }
  __syncthreads();
  if (ks == 0) {
#pragma unroll
    for (int r = 0; r < 4; r++) {
      float s = acc[r] + red[proj][qd * 4 + r][n16];
      size_t t = (size_t)(tile * 16 + qd * 4 + r) * HH + n16;
      if (proj == 0) beta[t] = 1.f / (1.f + expf(-s));
      else           graw[t] = s;
    }
  }
}

// ---------------------------------------------------------------------------
// K2: l2norm(q)*scale -> qn, l2norm(k) -> kn, beta*l2norm(k) -> kb  (bf16)
// ---------------------------------------------------------------------------
__global__ __launch_bounds__(256) void k2_l2norm(
    const float* __restrict__ q, const float* __restrict__ k,
    const float* __restrict__ beta,
    unsigned short* __restrict__ qn, unsigned short* __restrict__ kn,
    unsigned short* __restrict__ kb) {
  int lane = threadIdx.x & 63, wave = threadIdx.x >> 6;
  for (int u = 0; u < 2; u++) {
    int vec = blockIdx.x * 8 + wave * 2 + u;
    size_t off = (size_t)vec * 64 + lane;
    float2 q2 = ((const float2*)q)[off];
    float2 k2 = ((const float2*)k)[off];
    float bv = beta[vec];
    float sq = q2.x * q2.x + q2.y * q2.y;
    float sk = k2.x * k2.x + k2.y * k2.y;
#pragma unroll
    for (int m = 32; m; m >>= 1) { sq += __shfl_xor(sq, m); sk += __shfl_xor(sk, m); }
    float rq = rsqrtf(sq + 1e-6f) * QSCALE;
    float rk = rsqrtf(sk + 1e-6f);
    float rkb = rk * bv;
    unsigned pq = (unsigned)f2bf(q2.x * rq) | ((unsigned)f2bf(q2.y * rq) << 16);
    unsigned pk = (unsigned)f2bf(k2.x * rk) | ((unsigned)f2bf(k2.y * rk) << 16);
    unsigned pb = (unsigned)f2bf(k2.x * rkb) | ((unsigned)f2bf(k2.y * rkb) << 16);
    ((unsigned*)qn)[off] = pq;
    ((unsigned*)kn)[off] = pk;
    ((unsigned*)kb)[off] = pb;
  }
}

// ---------------------------------------------------------------------------
// K2v: vt = bf16(beta * v), transposed to the k4 C-fragment order:
//   vt[(bh*NN+n)*4 + rt][col 0..127][i 0..15] = beta[16rt+i]*v[t0+16rt+i][col]
// Runs AFTER k3 and overwrites the (dead) kn buffer.
// ---------------------------------------------------------------------------
__global__ __launch_bounds__(256) void k2v_vt(
    const float* __restrict__ v, const float* __restrict__ beta,
    unsigned short* __restrict__ vt) {
  int bi = blockIdx.x;                 // BB*HH*NN = 2048
  int n = bi & (NN - 1);
  int bh = bi >> 6;
  int h = bh & (HH - 1);
  int b = bh >> 4;
  int tid = threadIdx.x;
  int t0 = n * CC;

  __shared__ float sov[64 * 132];
  __shared__ float sbv[64];

  for (int p = 0; p < 8; p++) {
    int idx = p * 256 + tid;           // 2048 float4 quads
    int row = idx >> 5, d4 = (idx & 31) << 2;
    float4 x = *(const float4*)(v + ((size_t)((b * TT + t0 + row) * HH + h)) * DVv + d4);
    *(float4*)&sov[row * 132 + d4] = x;
  }
  if (tid < 64) sbv[tid] = beta[(size_t)((b * TT + t0 + tid) * HH + h)];
  __syncthreads();

  unsigned short* dst = vt + (size_t)(bh * NN + n) * 8192;  // 4*128*16 shorts
  for (int p = 0; p < 8; p++) {
    int q = p * 256 + tid;             // 2048 uint2
    int rt = q >> 9, col = (q >> 2) & 127, i4 = q & 3;
    int m = rt * 16 + i4 * 4;
    float x0 = sbv[m + 0] * sov[(m + 0) * 132 + col];
    float x1 = sbv[m + 1] * sov[(m + 1) * 132 + col];
    float x2 = sbv[m + 2] * sov[(m + 2) * 132 + col];
    float x3 = sbv[m + 3] * sov[(m + 3) * 132 + col];
    uint2 wv;
    wv.x = cvtpk(x0, x1);
    wv.y = cvtpk(x2, x3);
    *(uint2*)&dst[(size_t)q * 4] = wv;   // byte addr = q*8: fully coalesced
  }
}

// ---------------------------------------------------------------------------
// K3 (MFMA): per chunk: attn = tril(q k^T), A = tril(k_beta k^T,-1),
//   T = (I+A)^{-1} via nilpotent doubling, then:
//     ATg = attn @ T   [64 x 64]
//     Ktg = k^T @ T    [128 x 64] (row-major in dk)
// ---------------------------------------------------------------------------
#define SW 72          // stride (shorts) of 64x64 bf16 mats
#define K3_M0R 8704
#define K3_M0T 13312
#define K3_M1R 17920
#define K3_M1T 22528
#define K3_TB  27136   // T^T (col-major shadow of T), bf16
#define K3_ARENA 31744 // 63488 B

__global__ __launch_bounds__(256) void k3_chunk(
    const unsigned short* __restrict__ qn, const unsigned short* __restrict__ kn,
    const float* __restrict__ beta,
    unsigned short* __restrict__ ATg, unsigned short* __restrict__ Ktg) {
  int cid = blockIdx.x;
  int n = cid & (NN - 1);
  int bh = cid / NN;
  int h = bh & (HH - 1);
  int b = bh / HH;
  int tid = threadIdx.x;
  int w = tid >> 6;
  int lane = tid & 63;
  int n16 = lane & 15;
  int qd = lane >> 4;
  int r0 = w * 16;

  __shared__ __align__(16) unsigned short arena[K3_ARENA];
  __shared__ float sb[CC];
  unsigned short* sk = arena;           // [c][dk] stride 136, LIVE throughout
  unsigned short* sq = arena + 8704;    // aliased by M buffers after attn

  int t0 = n * CC;
#pragma unroll
  for (int p = 0; p < 4; p++) {
    int id = p * 256 + tid, row = id >> 4, c8 = (id & 15) << 3;
    size_t g = ((size_t)((b * TT + t0 + row) * HH + h)) * DKk + c8;
    *(uint4*)&sk[row * 136 + c8] = *(const uint4*)(kn + g);
    *(uint4*)&sq[row * 136 + c8] = *(const uint4*)(qn + g);
  }
  if (tid < CC) sb[tid] = beta[(size_t)((b * TT + t0 + tid) * HH + h)];
  __syncthreads();

  // ---- attn = q k^T and raw kk = k k^T   (MFMA, K=128)
  f4 at[4], mk[4];
#pragma unroll
  for (int ct = 0; ct < 4; ct++) { at[ct] = (f4){0,0,0,0}; mk[ct] = (f4){0,0,0,0}; }
#pragma unroll
  for (int s = 0; s < 4; s++) {
    bf8 aq = *(const bf8*)&sq[(r0 + n16) * 136 + s * 32 + qd * 8];
    bf8 ak = *(const bf8*)&sk[(r0 + n16) * 136 + s * 32 + qd * 8];
#pragma unroll
    for (int ct = 0; ct < 4; ct++) {
      bf8 bk = *(const bf8*)&sk[(ct * 16 + n16) * 136 + s * 32 + qd * 8];
      at[ct] = __builtin_amdgcn_mfma_f32_16x16x32_bf16(aq, bk, at[ct], 0, 0, 0);
      mk[ct] = __builtin_amdgcn_mfma_f32_16x16x32_bf16(ak, bk, mk[ct], 0, 0, 0);
    }
  }

  f4 tf[4];
  float mpv[4][4];
#pragma unroll
  for (int ct = 0; ct < 4; ct++) {
#pragma unroll
    for (int r = 0; r < 4; r++) {
      int i = r0 + qd * 4 + r, j = ct * 16 + n16;
      at[ct][r] = (j <= i) ? at[ct][r] : 0.f;      // masked attn kept in regs
      float mp = (j < i) ? -sb[i] * mk[ct][r] : 0.f;
      mpv[ct][r] = mp;
      tf[ct][r] = (i == j) ? 1.f : mp;
    }
  }
  __syncthreads();   // reads of sq done; M region usable

#pragma unroll
  for (int ct = 0; ct < 4; ct++) {
#pragma unroll
    for (int r = 0; r < 4; r++) {
      int i = r0 + qd * 4 + r, j = ct * 16 + n16;
      unsigned short hm = f2bf(mpv[ct][r]);
      arena[K3_M0R + i * SW + j] = hm;
      arena[K3_M0T + j * SW + i] = hm;
      arena[K3_TB + j * SW + i] = f2bf(tf[ct][r]);
    }
  }
  __syncthreads();

  int p = 0;
  for (int it = 1; it <= 5; it++) {
    int mrp = p ? K3_M1R : K3_M0R, mtp = p ? K3_M1T : K3_M0T;
    int mrn = p ? K3_M0R : K3_M1R, mtn = p ? K3_M0T : K3_M1T;
    f4 nr[4];
#pragma unroll
    for (int ct = 0; ct < 4; ct++) nr[ct] = (f4){0,0,0,0};
#pragma unroll
    for (int s = 0; s < 2; s++) {
      bf8 a = *(const bf8*)&arena[mrp + (r0 + n16) * SW + s * 32 + qd * 8];
#pragma unroll
      for (int ct = 0; ct < 4; ct++) {
        bf8 bb = *(const bf8*)&arena[mtp + (ct * 16 + n16) * SW + s * 32 + qd * 8];
        nr[ct] = __builtin_amdgcn_mfma_f32_16x16x32_bf16(a, bb, nr[ct], 0, 0, 0);
      }
    }
#pragma unroll
    for (int ct = 0; ct < 4; ct++) {
#pragma unroll
      for (int r = 0; r < 4; r++) {
        int i = r0 + qd * 4 + r, j = ct * 16 + n16;
        unsigned short hm = f2bf(nr[ct][r]);
        arena[mrn + i * SW + j] = hm;
        arena[mtn + j * SW + i] = hm;
      }
    }
    __syncthreads();  // B1

    // phase B: Tf += N · T
#pragma unroll
    for (int s = 0; s < 2; s++) {
      bf8 a = *(const bf8*)&arena[mrn + (r0 + n16) * SW + s * 32 + qd * 8];
#pragma unroll
      for (int ct = 0; ct < 4; ct++) {
        bf8 bb = *(const bf8*)&arena[K3_TB + (ct * 16 + n16) * SW + s * 32 + qd * 8];
        tf[ct] = __builtin_amdgcn_mfma_f32_16x16x32_bf16(a, bb, tf[ct], 0, 0, 0);
      }
    }
    __syncthreads();  // B2

    if (it < 5) {
#pragma unroll
      for (int ct = 0; ct < 4; ct++) {
#pragma unroll
        for (int r = 0; r < 4; r++) {
          int i = r0 + qd * 4 + r, j = ct * 16 + n16;
          arena[K3_TB + j * SW + i] = f2bf(tf[ct][r]);
        }
      }
    }
    p = 1 - p;
  }

  // ---- post-loop: attn -> M0R (dead), FINAL T^T -> TB
#pragma unroll
  for (int ct = 0; ct < 4; ct++) {
#pragma unroll
    for (int r = 0; r < 4; r++) {
      int i = r0 + qd * 4 + r, j = ct * 16 + n16;
      arena[K3_M0R + i * SW + j] = f2bf(at[ct][r]);
      arena[K3_TB + j * SW + i] = f2bf(tf[ct][r]);
    }
  }
  __syncthreads();

  // ---- ATg = attn @ T
  {
    f4 ac[4];
#pragma unroll
    for (int ct = 0; ct < 4; ct++) ac[ct] = (f4){0,0,0,0};
#pragma unroll
    for (int s = 0; s < 2; s++) {
      bf8 a = *(const bf8*)&arena[K3_M0R + (r0 + n16) * SW + s * 32 + qd * 8];
#pragma unroll
      for (int ct = 0; ct < 4; ct++) {
        bf8 bb = *(const bf8*)&arena[K3_TB + (ct * 16 + n16) * SW + s * 32 + qd * 8];
        ac[ct] = __builtin_amdgcn_mfma_f32_16x16x32_bf16(a, bb, ac[ct], 0, 0, 0);
      }
    }
    size_t abase = (size_t)cid * (CC * CC);
#pragma unroll
    for (int ct = 0; ct < 4; ct++)
#pragma unroll
      for (int r = 0; r < 4; r++)
        ATg[abase + (r0 + qd * 4 + r) * CC + ct * 16 + n16] = f2bf(ac[ct][r]);
  }

  // ---- Ktg = k^T @ T   (wave w owns dk rows w*32..w*32+31)
  {
    size_t kbase = (size_t)cid * (DKk * CC);
#pragma unroll
    for (int t = 0; t < 2; t++) {
      int dkt = w * 32 + t * 16;
      f4 ac[4];
#pragma unroll
      for (int ct = 0; ct < 4; ct++) ac[ct] = (f4){0,0,0,0};
#pragma unroll
      for (int s = 0; s < 2; s++) {
        bf8 a;
#pragma unroll
        for (int jj = 0; jj < 8; jj++)
          a[jj] = (short)sk[(s * 32 + qd * 8 + jj) * 136 + dkt + n16];
#pragma unroll
        for (int ct = 0; ct < 4; ct++) {
          bf8 bb = *(const bf8*)&arena[K3_TB + (ct * 16 + n16) * SW + s * 32 + qd * 8];
          ac[ct] = __builtin_amdgcn_mfma_f32_16x16x32_bf16(a, bb, ac[ct], 0, 0, 0);
        }
      }
#pragma unroll
      for (int ct = 0; ct < 4; ct++)
#pragma unroll
        for (int r = 0; r < 4; r++)
          Ktg[kbase + (dkt + qd * 4 + r) * CC + ct * 16 + n16] = f2bf(ac[ct][r]);
    }
  }
}

// ---------------------------------------------------------------------------
// K4 (MFMA): sequential chunk scan, R7: ONE barrier per chunk.
//   - kb (beta*k) staged in LDS in fragment layout (lane-linear, conflict-
//     free), double-buffered, regs loaded 2 chunks ahead.
//   - every wave computes ALL 64 rows of x redundantly (16 MFMA) -> x never
//     crosses waves; the transpose round-trip uses a wave-PRIVATE buffer
//     (in-order DS pipe, no barrier).
//   - S^T double-buffered in LDS: the single lgkm-barrier per chunk both
//     publishes S(n) and fences kb staging.
//   - q/AT/Kt fragments + vt (pre-transposed beta*v) direct global->reg.
// ---------------------------------------------------------------------------
struct K4F {
  bf8 q0, q1, q2, q3;      // qn rows r0+n16
  bf8 a0, a1;              // ATg rows r0+n16
  bf8 t0, t1, t2, t3;      // Ktg rows dkbase+n16 / dkbase+16+n16
  uint2 v0, v1, v2, v3;    // vt C-frag slices (beta*v, bf16)
};

static __device__ __forceinline__ void k4_pref(
    K4F& F, int n,
    const unsigned short* qnb, const unsigned short* atb,
    const unsigned short* ktb, const unsigned short* vtb) {
  const unsigned short* qp = qnb + (size_t)n * (CC * HH * DKk);
  F.q0 = *(const bf8*)(qp);
  F.q1 = *(const bf8*)(qp + 32);
  F.q2 = *(const bf8*)(qp + 64);
  F.q3 = *(const bf8*)(qp + 96);
  const unsigned short* ap = atb + (size_t)n * (CC * CC);
  F.a0 = *(const bf8*)(ap);
  F.a1 = *(const bf8*)(ap + 32);
  const unsigned short* tp = ktb + (size_t)n * (DKk * CC);
  F.t0 = *(const bf8*)(tp);
  F.t1 = *(const bf8*)(tp + 32);
  F.t2 = *(const bf8*)(tp + 1024);
  F.t3 = *(const bf8*)(tp + 1056);
  const unsigned short* vp = vtb + (size_t)n * 8192;
  F.v0 = *(const uint2*)(vp);
  F.v1 = *(const uint2*)(vp + 2048);
  F.v2 = *(const uint2*)(vp + 4096);
  F.v3 = *(const uint2*)(vp + 6144);
}

static __device__ __forceinline__ void k4_body(
    const K4F& F, K4F& FN, int n,
    f4& S0, f4& S1, uint4* KB,
    const unsigned short* sSrd, unsigned short* sSwr,
    const unsigned short* kbRd, unsigned short* kbWr,
    unsigned short* xbw, float* opn,
    int tid, int lane, int n16, int qd, int dkbase,
    const unsigned short* qnb, const unsigned short* atb,
    const unsigned short* ktb, const unsigned short* vtb,
    const unsigned short* kbg, const size_t* gkb) {
  // ---- stage kbL[wr] with chunk n+1 (KB loaded during chunk n-1)
  if (n + 1 < NN) {
#pragma unroll
    for (int p = 0; p < 4; p++)
      *(uint4*)&kbWr[(size_t)(p * 256 + tid) * 8] = KB[p];
  }
  // ---- reload KB <- chunk n+2 (consumed chunk n+1)
  if (n + 2 < NN) {
#pragma unroll
    for (int p = 0; p < 4; p++)
      KB[p] = *(const uint4*)(kbg + gkb[p] + (size_t)(n + 2) * (CC * HH * DKk));
  }
  // ---- prefetch chunk n+1 per-lane fragments
  if (n + 1 < NN) k4_pref(FN, n + 1, qnb, atb, ktb, vtb);

  // ---- S B-frags (published by previous chunk, fenced by barrier)
  bf8 bS0 = *(const bf8*)&sSrd[n16 * 136 + 0  + qd * 8];
  bf8 bS1 = *(const bf8*)&sSrd[n16 * 136 + 32 + qd * 8];
  bf8 bS2 = *(const bf8*)&sSrd[n16 * 136 + 64 + qd * 8];
  bf8 bS3 = *(const bf8*)&sSrd[n16 * 136 + 96 + qd * 8];

  // ---- o_inter = q @ S_old  (own 16 rows)
  f4 oa = {0.f, 0.f, 0.f, 0.f}, ob = {0.f, 0.f, 0.f, 0.f};
  oa = __builtin_amdgcn_mfma_f32_16x16x32_bf16(F.q0, bS0, oa, 0, 0, 0);
  oa = __builtin_amdgcn_mfma_f32_16x16x32_bf16(F.q1, bS1, oa, 0, 0, 0);
  ob = __builtin_amdgcn_mfma_f32_16x16x32_bf16(F.q2, bS2, ob, 0, 0, 0);
  ob = __builtin_amdgcn_mfma_f32_16x16x32_bf16(F.q3, bS3, ob, 0, 0, 0);

  // ---- x = beta*v - kb @ S_old, ALL 64 rows (redundant per wave)
  f4 xlo[4], xhi[4];
#pragma unroll
  for (int rt = 0; rt < 4; rt++) {
    bf8 kf0 = *(const bf8*)&kbRd[(size_t)((rt * 4 + 0) * 64 + lane) * 8];
    bf8 kf1 = *(const bf8*)&kbRd[(size_t)((rt * 4 + 1) * 64 + lane) * 8];
    bf8 kf2 = *(const bf8*)&kbRd[(size_t)((rt * 4 + 2) * 64 + lane) * 8];
    bf8 kf3 = *(const bf8*)&kbRd[(size_t)((rt * 4 + 3) * 64 + lane) * 8];
    f4 lo = {0.f, 0.f, 0.f, 0.f}, hi = {0.f, 0.f, 0.f, 0.f};
    lo = __builtin_amdgcn_mfma_f32_16x16x32_bf16(kf0, bS0, lo, 0, 0, 0);
    lo = __builtin_amdgcn_mfma_f32_16x16x32_bf16(kf1, bS1, lo, 0, 0, 0);
    hi = __builtin_amdgcn_mfma_f32_16x16x32_bf16(kf2, bS2, hi, 0, 0, 0);
    hi = __builtin_amdgcn_mfma_f32_16x16x32_bf16(kf3, bS3, hi, 0, 0, 0);
    xlo[rt] = lo;
    xhi[rt] = hi;
  }
  {
    const uint2 vv[4] = {F.v0, F.v1, F.v2, F.v3};
#pragma unroll
    for (int rt = 0; rt < 4; rt++) {
      float w0 = bf2f((unsigned short)(vv[rt].x & 0xffffu));
      float w1 = bf2f((unsigned short)(vv[rt].x >> 16));
      float w2 = bf2f((unsigned short)(vv[rt].y & 0xffffu));
      float w3 = bf2f((unsigned short)(vv[rt].y >> 16));
      bf4 pw = pack_bf4(w0 - (xlo[rt][0] + xhi[rt][0]),
                        w1 - (xlo[rt][1] + xhi[rt][1]),
                        w2 - (xlo[rt][2] + xhi[rt][2]),
                        w3 - (xlo[rt][3] + xhi[rt][3]));
      *(bf4*)&xbw[n16 * 88 + rt * 16 + qd * 4] = pw;   // wave-private
    }
  }
  // wave-private transpose read (same-wave ds_write -> ds_read, short-typed)
  bf8 bx0 = *(const bf8*)&xbw[n16 * 88 + 0  + qd * 8];
  bf8 bx1 = *(const bf8*)&xbw[n16 * 88 + 32 + qd * 8];

  // ---- o = o_inter + AT @ x -> global
  f4 oacc = oa + ob;
  oacc = __builtin_amdgcn_mfma_f32_16x16x32_bf16(F.a0, bx0, oacc, 0, 0, 0);
  oacc = __builtin_amdgcn_mfma_f32_16x16x32_bf16(F.a1, bx1, oacc, 0, 0, 0);
#pragma unroll
  for (int r = 0; r < 4; r++) opn[r * (HH * DVv)] = oacc[r];

  // ---- S += Kt @ x   (f32 accumulators, wave owns 32 dk rows)
  S0 = __builtin_amdgcn_mfma_f32_16x16x32_bf16(F.t0, bx0, S0, 0, 0, 0);
  S0 = __builtin_amdgcn_mfma_f32_16x16x32_bf16(F.t1, bx1, S0, 0, 0, 0);
  S1 = __builtin_amdgcn_mfma_f32_16x16x32_bf16(F.t2, bx0, S1, 0, 0, 0);
  S1 = __builtin_amdgcn_mfma_f32_16x16x32_bf16(F.t3, bx1, S1, 0, 0, 0);

  // ---- publish S(n) -> sSb[wr]
  *(bf4*)&sSwr[n16 * 136 + dkbase + qd * 4] =
      pack_bf4(S0[0], S0[1], S0[2], S0[3]);
  *(bf4*)&sSwr[n16 * 136 + dkbase + 16 + qd * 4] =
      pack_bf4(S1[0], S1[1], S1[2], S1[3]);

  barrier_lds_only();   // the ONE barrier: S(n) + kb(n+1) visible
}

__global__ __launch_bounds__(256, 1) void k4_scan(
    const unsigned short* __restrict__ qn, const unsigned short* __restrict__ kb,
    const unsigned short* __restrict__ vt,
    const unsigned short* __restrict__ ATg, const unsigned short* __restrict__ Ktg,
    float* __restrict__ o) {
  int bi = blockIdx.x;                 // jg*32 + bh (same-bh blocks share XCD)
  int jg = bi >> 5;
  int bh = bi & 31;
  int h = bh & (HH - 1);
  int b = bh >> 4;
  int tid = threadIdx.x;
  int j0 = jg * 16;
  int w = tid >> 6;
  int lane = tid & 63;
  int n16 = lane & 15;
  int qd = lane >> 4;
  int r0 = w * 16;                     // chunk-row tile of this wave
  int dkbase = w * 32;                 // S dk-rows owned by this wave

  __shared__ __align__(16) unsigned short sSb[2][16 * 136];  // 2x4352 B S^T
  __shared__ __align__(16) unsigned short kbL[2][CC * DKk];  // 2x16 KB frag-layout
  __shared__ __align__(16) unsigned short xbuf[4][16 * 88];  // wave-private x^T

  f4 S0 = {0.f, 0.f, 0.f, 0.f}, S1 = {0.f, 0.f, 0.f, 0.f};
  for (int i = tid; i < 2 * 16 * 136; i += 256) ((unsigned short*)sSb)[i] = 0;

  // lane-adjusted base pointers (chunk 0)
  const unsigned short* qnb =
      qn + ((size_t)((b * TT + r0 + n16) * HH + h)) * DKk + qd * 8;
  size_t bhN = (size_t)(b * HH + h) * NN;
  const unsigned short* atb = ATg + bhN * (CC * CC) + (r0 + n16) * 64 + qd * 8;
  const unsigned short* ktb = Ktg + bhN * (DKk * CC) + (dkbase + n16) * 64 + qd * 8;
  const unsigned short* vtb = vt + bhN * 8192 + (size_t)(j0 + n16) * 16 + qd * 4;
  float* opb =
      o + ((size_t)((b * TT + r0 + qd * 4) * HH + h)) * DVv + j0 + n16;

  // kb staging addresses: thread stages frag slot p*256+tid
  //   rt = p, s = w, row = p*16+n16, c8 = w*32+qd*8
  size_t gkb[4];
#pragma unroll
  for (int p = 0; p < 4; p++)
    gkb[p] = ((size_t)((b * TT + p * 16 + n16) * HH + h)) * DKk + w * 32 + qd * 8;

  uint4 KB[4];
  K4F FA, FB;
  unsigned short* xbw = xbuf[w];

  // prologue: kbL[0] <- chunk 0; KB <- chunk 1; FA <- chunk 0
#pragma unroll
  for (int p = 0; p < 4; p++) KB[p] = *(const uint4*)(kb + gkb[p]);
#pragma unroll
  for (int p = 0; p < 4; p++)
    *(uint4*)&kbL[0][(size_t)(p * 256 + tid) * 8] = KB[p];
#pragma unroll
  for (int p = 0; p < 4; p++)
    KB[p] = *(const uint4*)(kb + gkb[p] + (size_t)(CC * HH * DKk));
  k4_pref(FA, 0, qnb, atb, ktb, vtb);
  __syncthreads();

  for (int n = 0; n < NN; n += 2) {
    k4_body(FA, FB, n, S0, S1, KB, sSb[0], sSb[1], kbL[0], kbL[1],
            xbw, opb + (size_t)n * (CC * HH * DVv),
            tid, lane, n16, qd, dkbase, qnb, atb, ktb, vtb, kb, gkb);
    k4_body(FB, FA, n + 1, S0, S1, KB, sSb[1], sSb[0], kbL[1], kbL[0],
            xbw, opb + (size_t)(n + 1) * (CC * HH * DVv),
            tid, lane, n16, qd, dkbase, qnb, atb, ktb, vtb, kb, gkb);
  }
}

// ---------------------------------------------------------------------------
// K5: in-place on d_out: RMSNorm(o)*o_norm_w * swish(g), then per-head
//     projection via MFMA with pre-transposed Ppt[h][d][v] bf16.
// ---------------------------------------------------------------------------
__global__ __launch_bounds__(256) void k5_out(
    const float* __restrict__ graw, const float* __restrict__ onw,
    const unsigned short* __restrict__ Ppt, float* __restrict__ out) {
  int bi = blockIdx.x;                  // B*(T/32)*H = 4096
  int h = bi & (HH - 1);
  int tt = (bi >> 4) & 127;
  int b = bi >> 11;
  int t0 = tt * 32;
  int tid = threadIdx.x;
  int w = tid >> 6;
  int lane = tid & 63;
  int n16 = lane & 15;
  int qd = lane >> 4;

  __shared__ __align__(16) float so[32 * 132];            // 16896 B
  __shared__ float smul[32];
  __shared__ float snw[DVv];

  for (int r = 0; r < 16; r++) {
    int idx = r * 256 + tid;
    int t = idx >> 7, d = idx & 127;
    so[t * 132 + d] = out[((size_t)((b * TT + t0 + t) * HH + h)) * DVv + d];
  }
  if (tid < DVv) snw[tid] = onw[tid];
  __syncthreads();

  {
    int t = tid >> 3, l8 = tid & 7;
    float ss = 0.f;
    for (int j = 0; j < 16; j++) { float x = so[t * 132 + l8 + (j << 3)]; ss += x * x; }
    ss += __shfl_down(ss, 4, 8);
    ss += __shfl_down(ss, 2, 8);
    ss += __shfl_down(ss, 1, 8);
    if (l8 == 0) {
      float rms = rsqrtf(ss * (1.f / 128.f) + 1e-5f);
      float gv = graw[(size_t)((b * TT + t0 + t) * HH + h)];
      float sig = 1.f / (1.f + expf(-gv));
      smul[t] = rms * gv * sig;
    }
  }
  __syncthreads();
  for (int r = 0; r < 16; r++) {
    int idx = r * 256 + tid;
    int t = idx >> 7, d = idx & 127;
    so[t * 132 + d] *= smul[t] * snw[d];
  }
  __syncthreads();

  // ---- projection: out[t][d] = sum_v o~[t][v] * P[v][d]  (MFMA)
  {
    const unsigned short* Pb = Ppt + (size_t)h * (DVv * DKk);
    int dt0 = w * 2;                    // wave's two 16-col d-tiles
#pragma unroll
    for (int m = 0; m < 2; m++) {
      bf8 A[4];
#pragma unroll
      for (int ks = 0; ks < 4; ks++) {
        const float* sp = &so[(m * 16 + n16) * 132 + ks * 32 + qd * 8];
        float4 f0 = *(const float4*)sp;
        float4 f1 = *(const float4*)(sp + 4);
        A[ks][0] = (short)f2bf(f0.x); A[ks][1] = (short)f2bf(f0.y);
        A[ks][2] = (short)f2bf(f0.z); A[ks][3] = (short)f2bf(f0.w);
        A[ks][4] = (short)f2bf(f1.x); A[ks][5] = (short)f2bf(f1.y);
        A[ks][6] = (short)f2bf(f1.z); A[ks][7] = (short)f2bf(f1.w);
      }
#pragma unroll
      for (int dti = 0; dti < 2; dti++) {
        int dt = dt0 + dti;
        f4 acc = {0.f, 0.f, 0.f, 0.f};
#pragma unroll
        for (int ks = 0; ks < 4; ks++) {
          bf8 Bf = *(const bf8*)(Pb + (dt * 16 + n16) * 128 + ks * 32 + qd * 8);
          acc = __builtin_amdgcn_mfma_f32_16x16x32_bf16(A[ks], Bf, acc, 0, 0, 0);
        }
#pragma unroll
        for (int r = 0; r < 4; r++) {
          size_t go = ((size_t)(b * TT + t0 + m * 16 + qd * 4 + r)) * (HH * DKk)
                      + h * DKk + dt * 16 + n16;
          out[go] = acc[r];
        }
      }
    }
  }
}

// ---------------------------------------------------------------------------
extern "C" void kernel_launch(void* const* d_in, const int* in_sizes, int n_in,
                              void* d_out, int out_size, void* d_ws, size_t ws_size,
                              hipStream_t stream) {
  (void)in_sizes; (void)n_in; (void)out_size; (void)ws_size;
  const float* hab = (const float*)d_in[0];
  const float* hg  = (const float*)d_in[1];
  const float* q   = (const float*)d_in[2];
  const float* k   = (const float*)d_in[3];
  const float* v   = (const float*)d_in[4];
  const float* Wb  = (const float*)d_in[5];
  const float* Wg  = (const float*)d_in[6];
  const float* onw = (const float*)d_in[7];
  const float* opw = (const float*)d_in[8];
  float* out = (float*)d_out;

  // ws layout (bytes):
  //   beta 512K | graw 512K | qn 32MiB | kn/vt 32MiB (kn for k3, then k2v
  //   overwrites with vt) | ATg 16MiB | Ktg 32MiB | Wtb 64K | Wtg 64K |
  //   Ppt 512K | kb 32MiB   (total ~146 MB)
  char* ws = (char*)d_ws;
  float* beta          = (float*)(ws);
  float* graw          = (float*)(ws + 524288);
  unsigned short* qn   = (unsigned short*)(ws + 1048576);
  unsigned short* kn   = (unsigned short*)(ws + 34603008);
  unsigned short* vt   = kn;   // aliased: kn dead after k3
  unsigned short* ATg  = (unsigned short*)(ws + 68157440);
  unsigned short* Ktg  = (unsigned short*)(ws + 84934656);
  unsigned short* Wtb  = (unsigned short*)(ws + 118489088);
  unsigned short* Wtg  = (unsigned short*)(ws + 118554624);
  unsigned short* Ppt  = (unsigned short*)(ws + 118620160);
  unsigned short* kb   = (unsigned short*)(ws + 119144448);

  hipLaunchKernelGGL(k0_wt, dim3(16), dim3(256), 0, stream,
                     Wb, Wg, Wtb, Wtg);
  hipLaunchKernelGGL(k0p_pt, dim3(HH), dim3(256), 0, stream,
                     opw, Ppt);
  hipLaunchKernelGGL(k1_beta_g, dim3(TT * BB / 16), dim3(256), 0, stream,
                     hab, hg, Wtb, Wtg, beta, graw);
  hipLaunchKernelGGL(k2_l2norm, dim3(BB * TT * HH / 8), dim3(256), 0, stream,
                     q, k, beta, qn, kn, kb);
  hipLaunchKernelGGL(k3_chunk, dim3(BB * HH * NN), dim3(256), 0, stream,
                     qn, kn, beta, ATg, Ktg);
  hipLaunchKernelGGL(k2v_vt, dim3(BB * HH * NN), dim3(256), 0, stream,
                     v, beta, vt);
  hipLaunchKernelGGL(k4_scan, dim3(BB * HH * GG), dim3(256), 0, stream,
                     qn, kb, vt, ATg, Ktg, out);
  hipLaunchKernelGGL(k5_out, dim3(BB * (TT / 32) * HH), dim3(256), 0, stream,
                     graw, onw, Ppt, out);
}